// Round 20
// baseline (162.477 us; speedup 1.0000x reference)
//
#include <hip/hip_runtime.h>

// Problem constants
#define B_  4
#define S_  2048
#define D_  1024
#define H_  16
#define HD_ 64
#define M_  (B_*S_)   // 8192 rows total

typedef _Float16 f16;
typedef f16  f16x8 __attribute__((ext_vector_type(8)));
typedef f16  f16x4 __attribute__((ext_vector_type(4)));
typedef float f32x4 __attribute__((ext_vector_type(4)));

// global -> LDS direct DMA, 16B per lane. LDS dest = wave-uniform base + lane*16.
__device__ __forceinline__ void gload_lds16(const f16* g, f16* l) {
    __builtin_amdgcn_global_load_lds(
        (const __attribute__((address_space(1))) void*)g,
        (__attribute__((address_space(3))) void*)l, 16, 0, 0);
}

// ---------------------------------------------------------------- converts (fused, grid-stride)
__global__ __launch_bounds__(256) void cvt2_kernel(const float* __restrict__ a,
                                                   const float* __restrict__ c,
                                                   f16* __restrict__ out, int n4each) {
    const int n4tot = 2 * n4each;
    for (int i = blockIdx.x * 256 + threadIdx.x; i < n4tot; i += gridDim.x * 256) {
        const float* src = (i < n4each) ? a : c;
        int j = (i < n4each) ? i : i - n4each;
        f32x4 v = *reinterpret_cast<const f32x4*>(src + (size_t)j * 4);
        *reinterpret_cast<f16x4*>(out + (size_t)i * 4) = __builtin_convertvector(v, f16x4);
    }
}

// all four weights W[K][N] f32 -> WT[N][K] f16 (outputs contiguous per z)
__global__ __launch_bounds__(256) void transpose_cvt4_kernel(const float* __restrict__ Wq,
                                                             const float* __restrict__ Wk,
                                                             const float* __restrict__ Wv,
                                                             const float* __restrict__ Wo,
                                                             f16* __restrict__ WT) {
    __shared__ float tile[32][33];
    const int z = blockIdx.z;
    const float* W = (z == 0) ? Wq : (z == 1) ? Wk : (z == 2) ? Wv : Wo;
    f16* dst = WT + (size_t)z * D_ * D_;
    const int n0 = blockIdx.x * 32, k0 = blockIdx.y * 32;
    const int tx = threadIdx.x & 31, ty = threadIdx.x >> 5; // (32,8)
#pragma unroll
    for (int j = 0; j < 4; ++j)
        tile[ty + 8 * j][tx] = W[(size_t)(k0 + ty + 8 * j) * D_ + n0 + tx];
    __syncthreads();
#pragma unroll
    for (int j = 0; j < 4; ++j)
        dst[(size_t)(n0 + ty + 8 * j) * D_ + k0 + tx] = (f16)tile[tx][ty + 8 * j];
}

// ---------------------------------------------------------------- triple-buffered GEMM, BM=128 x BN=256, BK=32
// (r16-measured config — QKV ~61 us, out ~12 us. Reverted from r18's inline-cvt:
//  reg-staged A-write put vmcnt->ds_write->lgkmcnt on the per-tile critical path
//  and doubled A fetch bytes; measured 97 us. DMA staging + separate cvt wins.)
// 256 threads = 4 waves (2M x 2N); per-wave 64x128 out (4m x 8n). LDS 72KB = 3 bufs.
// Depth-2 staging, counted vmcnt(6) (never drains mid-loop). 2 blocks/CU.
// MODE 0: QKV, 768 blocks, seg = id>>8 (0=Q,1=K,2=V sequential-ish rounds).
// MODE 1: output GEMM f32, 256 blocks.
template <int MODE>
__global__ __launch_bounds__(256, 2) void gemm3p(const f16* __restrict__ Adata,
                                                 const f16* __restrict__ Actx,
                                                 const f16* __restrict__ Wbase,
                                                 const float* __restrict__ b0,
                                                 const float* __restrict__ b1,
                                                 const float* __restrict__ b2,
                                                 f16* __restrict__ Qb,
                                                 f16* __restrict__ Kb,
                                                 f16* __restrict__ VtB,
                                                 float* __restrict__ Cout) {
    extern __shared__ __align__(16) f16 SM[]; // 3 x 12288 f16 (A 4096 + B 8192 each)
    constexpr int K = D_;
    constexpr int NT = K / 32;
    const int id = (int)blockIdx.x;
    const int seg = (MODE == 0) ? (id >> 8) : 0;       // 0=Q,1=K,2=V
    const int sid = (MODE == 0) ? (id & 255) : id;
    const int work = (sid & 7) * 32 + (sid >> 3);      // XCD-chunked, bijective
    const int wy = work >> 2, wx = work & 3;           // 64 x 4
    const f16* __restrict__ A = (MODE == 0) ? (seg ? Actx : Adata) : Adata;
    const f16* __restrict__ Wt = Wbase + (size_t)seg * D_ * D_;
    const int m0 = wy * 128, n0 = wx * 256;
    const int tid = (int)threadIdx.x;
    const int w = tid >> 6, lr = tid & 15, lg = (tid & 63) >> 4;
    const int wr = w >> 1, wc = w & 1;
    const int sw = (lr >> 1) & 3;

    auto stage = [&](int buf, int kt) {
        const int kk0 = kt * 32;
        f16* base = SM + buf * 12288;
#pragma unroll
        for (int j = 0; j < 2; ++j) {
            const int c = j * 256 + tid;
            const int row = c >> 2;
            const int ks = ((c & 3) ^ ((row >> 1) & 3)) * 8; // pre-swizzled k-slot
            gload_lds16(A + (size_t)(m0 + row) * K + kk0 + ks,
                        base + (j * 256 + w * 64) * 8);
        }
#pragma unroll
        for (int j = 0; j < 4; ++j) {
            const int c = j * 256 + tid;
            const int row = c >> 2;
            const int ks = ((c & 3) ^ ((row >> 1) & 3)) * 8;
            gload_lds16(Wt + (size_t)(n0 + row) * K + kk0 + ks,
                        base + 4096 + (j * 256 + w * 64) * 8);
        }
    };
    auto LDA = [&](int buf, int m) -> f16x8 {
        return *reinterpret_cast<const f16x8*>(
            SM + buf * 12288 + (wr * 64 + m * 16 + lr) * 32 + ((lg ^ sw) * 8));
    };
    auto LDB = [&](int buf, int n) -> f16x8 {
        return *reinterpret_cast<const f16x8*>(
            SM + buf * 12288 + 4096 + (wc * 128 + n * 16 + lr) * 32 + ((lg ^ sw) * 8));
    };

    f32x4 acc[4][8] = {};
    stage(0, 0);
    stage(1, 1);
    asm volatile("s_waitcnt vmcnt(6)" ::: "memory");
    __builtin_amdgcn_s_barrier();

    int buf = 0;
    for (int t = 0; t < NT; ++t) {
        if (t + 2 < NT) {
            int nb = buf + 2; if (nb >= 3) nb -= 3;
            stage(nb, t + 2);
        }
        f16x8 a[4], b[8];
#pragma unroll
        for (int m = 0; m < 4; ++m) a[m] = LDA(buf, m);
#pragma unroll
        for (int n = 0; n < 8; ++n) b[n] = LDB(buf, n);
        __builtin_amdgcn_s_setprio(1);
#pragma unroll
        for (int m = 0; m < 4; ++m)
#pragma unroll
            for (int n = 0; n < 8; ++n)
                acc[m][n] = __builtin_amdgcn_mfma_f32_16x16x32_f16(a[m], b[n], acc[m][n], 0, 0, 0);
        __builtin_amdgcn_s_setprio(0);
        if (t + 2 < NT) {
            asm volatile("s_waitcnt vmcnt(6)" ::: "memory");
        } else if (t + 1 < NT) {
            asm volatile("s_waitcnt vmcnt(0)" ::: "memory");
        }
        __builtin_amdgcn_s_barrier();
        if (++buf >= 3) buf = 0;
    }
    // ---- epilogue
    if (MODE == 1) {
#pragma unroll
        for (int n = 0; n < 8; ++n) {
            const int col = n0 + wc * 128 + n * 16 + lr;
            const float bvv = b0[col];
#pragma unroll
            for (int m = 0; m < 4; ++m) {
                const int row = m0 + wr * 64 + m * 16 + lg * 4;
#pragma unroll
                for (int r = 0; r < 4; ++r)
                    Cout[(size_t)(row + r) * D_ + col] = acc[m][n][r] + bvv;
            }
        }
    } else {
        const float* bias = (seg == 0) ? b0 : (seg == 1) ? b1 : b2;
#pragma unroll
        for (int n = 0; n < 8; ++n) {
            const int lc = n0 + wc * 128 + n * 16 + lr; // 0..1023 within segment
            const float bvv = bias[lc];
#pragma unroll
            for (int m = 0; m < 4; ++m) {
                const int row = m0 + wr * 64 + m * 16 + lg * 4;
                if (seg == 2) { // V transposed: VT[B][H*HD][S]
                    const int bb = row >> 11, s0 = row & 2047;
                    f16x4 v;
#pragma unroll
                    for (int r = 0; r < 4; ++r) v[r] = (f16)(acc[m][n][r] + bvv);
                    *reinterpret_cast<f16x4*>(VtB + ((size_t)(bb * D_ + lc)) * S_ + s0) = v;
                } else {
                    f16* dst = seg ? Kb : Qb;
#pragma unroll
                    for (int r = 0; r < 4; ++r)
                        dst[(size_t)(row + r) * D_ + lc] = (f16)(acc[m][n][r] + bvv);
                }
            }
        }
    }
}

// ---------------------------------------------------------------- causal flash attention (r19-measured, frozen)
// grid (H, B, 16): ONE 128-row q-tile per block, qt = 15 - z (heavy tiles first).
// id%8 = h%8 -> per-XCD K+V set = 4MB = L2-resident. LDS 50KB -> 3 blocks/CU.
__global__ __launch_bounds__(256, 3) void attn_kernel(const f16* __restrict__ Q,
                                                      const f16* __restrict__ Kg,
                                                      const f16* __restrict__ Vt,
                                                      f16* __restrict__ Z) {
    __shared__ __align__(16) f16 KL[2][64 * 64];
    __shared__ __align__(16) f16 VL[2][64 * 64];
    __shared__ __align__(16) f16 Pl[4][32][72];
    const int h = blockIdx.x, b = blockIdx.y;
    const int qt = 15 - (int)blockIdx.z; // heavy tiles dispatch first
    const int tid = threadIdx.x, w = tid >> 6, l = tid & 63, lr = l & 15, lg = l >> 4;
    const size_t base   = ((size_t)b * S_) * D_ + h * HD_;
    const size_t vtbase = ((size_t)(b * D_ + h * HD_)) * S_;
    const f16* __restrict__ Kbase = Kg + base;
    const f16* __restrict__ Vbase = Vt + vtbase;
    const float sc = 0.125f * 1.44269504f; // 1/sqrt(64) * log2(e)
    const int sw_xor = lr & 7;
    f16x8 onesv;
#pragma unroll
    for (int i = 0; i < 8; ++i) onesv[i] = (f16)1.0f;

    auto stageKV = [&](int buf, int t0) {
#pragma unroll
        for (int i = 0; i < 2; ++i) {
            const int c = i * 256 + tid;
            const int row = c >> 3, g16 = (c & 7) ^ (row & 7);
            f16* dstK = &KL[buf][(i * 256 + w * 64) * 8];
            f16* dstV = &VL[buf][(i * 256 + w * 64) * 8];
            gload_lds16(Kbase + (size_t)(t0 + row) * D_ + g16 * 8, dstK);
            gload_lds16(Vbase + (size_t)row * S_ + t0 + g16 * 8, dstV);
        }
    };

    const int q0 = qt * 128, wq0 = q0 + w * 32;
    const int ntw = ((wq0 + 31) >> 6) + 1;
    const int ntb = qt * 2 + 2;

    f16x8 qf[2][2];
#pragma unroll
    for (int mf = 0; mf < 2; ++mf)
#pragma unroll
        for (int kd = 0; kd < 2; ++kd)
            qf[mf][kd] = *reinterpret_cast<const f16x8*>(
                Q + base + (size_t)(wq0 + mf * 16 + lr) * D_ + kd * 32 + lg * 8);

    f32x4 zacc[2][4] = {};
    f32x4 lsv[2] = {};
    float mrun[2] = {-3.0e38f, -3.0e38f};

    stageKV(0, 0);
    for (int t = 0; t < ntb; ++t) {
        const int buf = t & 1;
        if (t + 1 < ntb) {
            stageKV(buf ^ 1, (t + 1) * 64);
            asm volatile("s_waitcnt vmcnt(4)" ::: "memory");
        } else {
            asm volatile("s_waitcnt vmcnt(0)" ::: "memory");
        }
        __builtin_amdgcn_s_barrier();
        if (t < ntw) {
            const int t0 = t * 64;
            f16x8 kf[2][4];
#pragma unroll
            for (int kd = 0; kd < 2; ++kd)
#pragma unroll
                for (int n = 0; n < 4; ++n)
                    kf[kd][n] = *reinterpret_cast<const f16x8*>(
                        &KL[buf][(n * 16 + lr) * 64 + (((kd * 4 + lg) ^ sw_xor) * 8)]);
            f32x4 sf[2][4] = {};
            __builtin_amdgcn_s_setprio(1);
#pragma unroll
            for (int kd = 0; kd < 2; ++kd)
#pragma unroll
                for (int n = 0; n < 4; ++n)
#pragma unroll
                    for (int mf = 0; mf < 2; ++mf)
                        sf[mf][n] = __builtin_amdgcn_mfma_f32_16x16x32_f16(kf[kd][n], qf[mf][kd], sf[mf][n], 0, 0, 0);
            __builtin_amdgcn_s_setprio(0);
            f16x8 vf[2][4];
#pragma unroll
            for (int kt = 0; kt < 2; ++kt)
#pragma unroll
                for (int n = 0; n < 4; ++n)
                    vf[kt][n] = *reinterpret_cast<const f16x8*>(
                        &VL[buf][(n * 16 + lr) * 64 + (((kt * 4 + lg) ^ sw_xor) * 8)]);
            if (t == ntw - 1) {
#pragma unroll
                for (int mf = 0; mf < 2; ++mf)
#pragma unroll
                    for (int n = 0; n < 4; ++n)
#pragma unroll
                        for (int r = 0; r < 4; ++r)
                            if ((t0 + n * 16 + lg * 4 + r) > (wq0 + mf * 16 + lr))
                                sf[mf][n][r] = -3.0e38f;
            }
#pragma unroll
            for (int mf = 0; mf < 2; ++mf) {
                f32x4 t4;
#pragma unroll
                for (int r = 0; r < 4; ++r)
                    t4[r] = fmaxf(fmaxf(sf[mf][0][r], sf[mf][1][r]), fmaxf(sf[mf][2][r], sf[mf][3][r]));
                float vmax = fmaxf(fmaxf(t4[0], t4[1]), fmaxf(t4[2], t4[3]));
                vmax = fmaxf(vmax, __shfl_xor(vmax, 16));
                vmax = fmaxf(vmax, __shfl_xor(vmax, 32));
                const float vs = vmax * sc;
                const bool norm = !__all(vs <= mrun[mf] + 10.0f);
                if (norm) {
                    const float mnew = fmaxf(mrun[mf], vs);
                    const float al = __builtin_amdgcn_exp2f(mrun[mf] - mnew);
                    mrun[mf] = mnew;
#pragma unroll
                    for (int r = 0; r < 4; ++r) {
                        const float ar = __shfl(al, lg * 4 + r);
#pragma unroll
                        for (int n = 0; n < 4; ++n) zacc[mf][n][r] *= ar;
                        lsv[mf][r] *= ar;
                    }
                }
#pragma unroll
                for (int n = 0; n < 4; ++n) {
                    f32x4 p;
#pragma unroll
                    for (int r = 0; r < 4; ++r)
                        p[r] = __builtin_amdgcn_exp2f(fmaf(sf[mf][n][r], sc, -mrun[mf]));
                    f16x4 pv;
#pragma unroll
                    for (int r = 0; r < 4; ++r) pv[r] = (f16)p[r];
                    *reinterpret_cast<f16x4*>(&Pl[w][mf * 16 + lr][n * 16 + lg * 4]) = pv;
                }
            }
#pragma unroll
            for (int kt = 0; kt < 2; ++kt) {
                f16x8 pa[2];
#pragma unroll
                for (int mf = 0; mf < 2; ++mf)
                    pa[mf] = *reinterpret_cast<const f16x8*>(&Pl[w][mf * 16 + lr][kt * 32 + lg * 8]);
                __builtin_amdgcn_s_setprio(1);
#pragma unroll
                for (int n = 0; n < 4; ++n)
#pragma unroll
                    for (int mf = 0; mf < 2; ++mf)
                        zacc[mf][n] = __builtin_amdgcn_mfma_f32_16x16x32_f16(pa[mf], vf[kt][n], zacc[mf][n], 0, 0, 0);
#pragma unroll
                for (int mf = 0; mf < 2; ++mf)
                    lsv[mf] = __builtin_amdgcn_mfma_f32_16x16x32_f16(pa[mf], onesv, lsv[mf], 0, 0, 0);
                __builtin_amdgcn_s_setprio(0);
            }
        }
        __builtin_amdgcn_s_barrier();
    }
#pragma unroll
    for (int mf = 0; mf < 2; ++mf) {
        f32x4 inv;
#pragma unroll
        for (int r = 0; r < 4; ++r) inv[r] = 1.0f / lsv[mf][r];
#pragma unroll
        for (int r = 0; r < 4; ++r)
#pragma unroll
            for (int n = 0; n < 4; ++n)
                Z[base + (size_t)(wq0 + mf * 16 + lg * 4 + r) * D_ + n * 16 + lr] =
                    (f16)(zacc[mf][n][r] * inv[r]);
    }
}

// ---------------------------------------------------------------- launcher
extern "C" void kernel_launch(void* const* d_in, const int* in_sizes, int n_in,
                              void* d_out, int out_size, void* d_ws, size_t ws_size,
                              hipStream_t stream) {
    const float* data    = (const float*)d_in[0];
    const float* context = (const float*)d_in[1];
    const float* Wq = (const float*)d_in[2];
    const float* bq = (const float*)d_in[3];
    const float* Wk = (const float*)d_in[4];
    const float* bk = (const float*)d_in[5];
    const float* Wv = (const float*)d_in[6];
    const float* bv = (const float*)d_in[7];
    const float* Wo = (const float*)d_in[8];
    const float* bo = (const float*)d_in[9];

    const size_t MD = (size_t)M_ * D_;
    const size_t DD = (size_t)D_ * D_;
    f16* dataB = (f16*)d_ws;
    f16* ctxB  = dataB + MD;
    f16* WqT   = ctxB + MD;   // WqT,WkT,WvT,WoT contiguous
    f16* WoT   = WqT + 3 * DD;
    f16* Qb    = WqT + 4 * DD;
    f16* Kb    = Qb + MD;
    f16* VtB   = Kb + MD;     // [B][H][HD][S]
    f16* Zb    = VtB + MD;

    const int n4 = (int)(MD / 4);
    cvt2_kernel<<<2048, 256, 0, stream>>>(data, context, dataB, n4);
    transpose_cvt4_kernel<<<dim3(32, 32, 4), 256, 0, stream>>>(Wq, Wk, Wv, Wo, WqT);

    (void)hipFuncSetAttribute(reinterpret_cast<const void*>(gemm3p<0>),
                              hipFuncAttributeMaxDynamicSharedMemorySize, 73728);
    (void)hipFuncSetAttribute(reinterpret_cast<const void*>(gemm3p<1>),
                              hipFuncAttributeMaxDynamicSharedMemorySize, 73728);

    // QKV: 768 blocks, seg = id>>8 (r16 measured ~61 us)
    gemm3p<0><<<768, 256, 73728, stream>>>(dataB, ctxB, WqT, bq, bk, bv,
                                           Qb, Kb, VtB, nullptr);

    attn_kernel<<<dim3(H_, B_, 16), 256, 0, stream>>>(Qb, Kb, VtB, Zb);

    gemm3p<1><<<256, 256, 73728, stream>>>(Zb, nullptr, WoT, bo, nullptr, nullptr,
                                           nullptr, nullptr, nullptr, (float*)d_out);
}

// Round 21
// 161.981 us; speedup vs baseline: 1.0031x; 1.0031x over previous
//
#include <hip/hip_runtime.h>

// Problem constants
#define B_  4
#define S_  2048
#define D_  1024
#define H_  16
#define HD_ 64
#define M_  (B_*S_)   // 8192 rows total

typedef _Float16 f16;
typedef f16  f16x8 __attribute__((ext_vector_type(8)));
typedef f16  f16x4 __attribute__((ext_vector_type(4)));
typedef float f32x4 __attribute__((ext_vector_type(4)));

// global -> LDS direct DMA, 16B per lane. LDS dest = wave-uniform base + lane*16.
__device__ __forceinline__ void gload_lds16(const f16* g, f16* l) {
    __builtin_amdgcn_global_load_lds(
        (const __attribute__((address_space(1))) void*)g,
        (__attribute__((address_space(3))) void*)l, 16, 0, 0);
}

// ---------------------------------------------------------------- converts (fused, grid-stride)
__global__ __launch_bounds__(256) void cvt2_kernel(const float* __restrict__ a,
                                                   const float* __restrict__ c,
                                                   f16* __restrict__ out, int n4each) {
    const int n4tot = 2 * n4each;
    for (int i = blockIdx.x * 256 + threadIdx.x; i < n4tot; i += gridDim.x * 256) {
        const float* src = (i < n4each) ? a : c;
        int j = (i < n4each) ? i : i - n4each;
        f32x4 v = *reinterpret_cast<const f32x4*>(src + (size_t)j * 4);
        *reinterpret_cast<f16x4*>(out + (size_t)i * 4) = __builtin_convertvector(v, f16x4);
    }
}

// all four weights W[K][N] f32 -> WT[N][K] f16 (outputs contiguous per z)
__global__ __launch_bounds__(256) void transpose_cvt4_kernel(const float* __restrict__ Wq,
                                                             const float* __restrict__ Wk,
                                                             const float* __restrict__ Wv,
                                                             const float* __restrict__ Wo,
                                                             f16* __restrict__ WT) {
    __shared__ float tile[32][33];
    const int z = blockIdx.z;
    const float* W = (z == 0) ? Wq : (z == 1) ? Wk : (z == 2) ? Wv : Wo;
    f16* dst = WT + (size_t)z * D_ * D_;
    const int n0 = blockIdx.x * 32, k0 = blockIdx.y * 32;
    const int tx = threadIdx.x & 31, ty = threadIdx.x >> 5; // (32,8)
#pragma unroll
    for (int j = 0; j < 4; ++j)
        tile[ty + 8 * j][tx] = W[(size_t)(k0 + ty + 8 * j) * D_ + n0 + tx];
    __syncthreads();
#pragma unroll
    for (int j = 0; j < 4; ++j)
        dst[(size_t)(n0 + ty + 8 * j) * D_ + k0 + tx] = (f16)tile[tx][ty + 8 * j];
}

// ---------------------------------------------------------------- triple-buffered GEMM, BM=128 x BN=256, BK=32
// 256 threads = 4 waves (2M x 2N); per-wave 64x128 out (4m x 8n). LDS 72KB = 3 bufs.
// Depth-2 staging, counted vmcnt(6) (never drains mid-loop). 2 blocks/CU.
// MODE 0: QKV, 768 blocks. Segment order K,V,Q (seg = (id>>8)==2 ? Q : (id>>8)+1):
//   the co-resident first pair K+V SHARES A=context (per-XCD set 6MB vs 8MB when
//   Q+K co-ran with disjoint A), and Q runs last alone at a clean 4MB/XCD.
// MODE 1: output GEMM f32, 256 blocks.
template <int MODE>
__global__ __launch_bounds__(256, 2) void gemm3p(const f16* __restrict__ Adata,
                                                 const f16* __restrict__ Actx,
                                                 const f16* __restrict__ Wbase,
                                                 const float* __restrict__ b0,
                                                 const float* __restrict__ b1,
                                                 const float* __restrict__ b2,
                                                 f16* __restrict__ Qb,
                                                 f16* __restrict__ Kb,
                                                 f16* __restrict__ VtB,
                                                 float* __restrict__ Cout) {
    extern __shared__ __align__(16) f16 SM[]; // 3 x 12288 f16 (A 4096 + B 8192 each)
    constexpr int K = D_;
    constexpr int NT = K / 32;
    const int id = (int)blockIdx.x;
    const int sg3 = (MODE == 0) ? (id >> 8) : 0;
    const int seg = (MODE == 0) ? ((sg3 == 2) ? 0 : sg3 + 1) : 0; // order: K,V,Q
    const int sid = (MODE == 0) ? (id & 255) : id;
    const int work = (sid & 7) * 32 + (sid >> 3);      // XCD-chunked, bijective
    const int wy = work >> 2, wx = work & 3;           // 64 x 4
    const f16* __restrict__ A = (MODE == 0) ? (seg ? Actx : Adata) : Adata;
    const f16* __restrict__ Wt = Wbase + (size_t)seg * D_ * D_;
    const int m0 = wy * 128, n0 = wx * 256;
    const int tid = (int)threadIdx.x;
    const int w = tid >> 6, lr = tid & 15, lg = (tid & 63) >> 4;
    const int wr = w >> 1, wc = w & 1;
    const int sw = (lr >> 1) & 3;

    auto stage = [&](int buf, int kt) {
        const int kk0 = kt * 32;
        f16* base = SM + buf * 12288;
#pragma unroll
        for (int j = 0; j < 2; ++j) {
            const int c = j * 256 + tid;
            const int row = c >> 2;
            const int ks = ((c & 3) ^ ((row >> 1) & 3)) * 8; // pre-swizzled k-slot
            gload_lds16(A + (size_t)(m0 + row) * K + kk0 + ks,
                        base + (j * 256 + w * 64) * 8);
        }
#pragma unroll
        for (int j = 0; j < 4; ++j) {
            const int c = j * 256 + tid;
            const int row = c >> 2;
            const int ks = ((c & 3) ^ ((row >> 1) & 3)) * 8;
            gload_lds16(Wt + (size_t)(n0 + row) * K + kk0 + ks,
                        base + 4096 + (j * 256 + w * 64) * 8);
        }
    };
    auto LDA = [&](int buf, int m) -> f16x8 {
        return *reinterpret_cast<const f16x8*>(
            SM + buf * 12288 + (wr * 64 + m * 16 + lr) * 32 + ((lg ^ sw) * 8));
    };
    auto LDB = [&](int buf, int n) -> f16x8 {
        return *reinterpret_cast<const f16x8*>(
            SM + buf * 12288 + 4096 + (wc * 128 + n * 16 + lr) * 32 + ((lg ^ sw) * 8));
    };

    f32x4 acc[4][8] = {};
    stage(0, 0);
    stage(1, 1);
    asm volatile("s_waitcnt vmcnt(6)" ::: "memory");
    __builtin_amdgcn_s_barrier();

    int buf = 0;
    for (int t = 0; t < NT; ++t) {
        if (t + 2 < NT) {
            int nb = buf + 2; if (nb >= 3) nb -= 3;
            stage(nb, t + 2);
        }
        f16x8 a[4], b[8];
#pragma unroll
        for (int m = 0; m < 4; ++m) a[m] = LDA(buf, m);
#pragma unroll
        for (int n = 0; n < 8; ++n) b[n] = LDB(buf, n);
        __builtin_amdgcn_s_setprio(1);
#pragma unroll
        for (int m = 0; m < 4; ++m)
#pragma unroll
            for (int n = 0; n < 8; ++n)
                acc[m][n] = __builtin_amdgcn_mfma_f32_16x16x32_f16(a[m], b[n], acc[m][n], 0, 0, 0);
        __builtin_amdgcn_s_setprio(0);
        if (t + 2 < NT) {
            asm volatile("s_waitcnt vmcnt(6)" ::: "memory");
        } else if (t + 1 < NT) {
            asm volatile("s_waitcnt vmcnt(0)" ::: "memory");
        }
        __builtin_amdgcn_s_barrier();
        if (++buf >= 3) buf = 0;
    }
    // ---- epilogue
    if (MODE == 1) {
#pragma unroll
        for (int n = 0; n < 8; ++n) {
            const int col = n0 + wc * 128 + n * 16 + lr;
            const float bvv = b0[col];
#pragma unroll
            for (int m = 0; m < 4; ++m) {
                const int row = m0 + wr * 64 + m * 16 + lg * 4;
#pragma unroll
                for (int r = 0; r < 4; ++r)
                    Cout[(size_t)(row + r) * D_ + col] = acc[m][n][r] + bvv;
            }
        }
    } else {
        const float* bias = (seg == 0) ? b0 : (seg == 1) ? b1 : b2;
#pragma unroll
        for (int n = 0; n < 8; ++n) {
            const int lc = n0 + wc * 128 + n * 16 + lr; // 0..1023 within segment
            const float bvv = bias[lc];
#pragma unroll
            for (int m = 0; m < 4; ++m) {
                const int row = m0 + wr * 64 + m * 16 + lg * 4;
                if (seg == 2) { // V transposed: VT[B][H*HD][S]
                    const int bb = row >> 11, s0 = row & 2047;
                    f16x4 v;
#pragma unroll
                    for (int r = 0; r < 4; ++r) v[r] = (f16)(acc[m][n][r] + bvv);
                    *reinterpret_cast<f16x4*>(VtB + ((size_t)(bb * D_ + lc)) * S_ + s0) = v;
                } else {
                    f16* dst = seg ? Kb : Qb;
#pragma unroll
                    for (int r = 0; r < 4; ++r)
                        dst[(size_t)(row + r) * D_ + lc] = (f16)(acc[m][n][r] + bvv);
                }
            }
        }
    }
}

// ---------------------------------------------------------------- causal flash attention (r19-measured, frozen)
// grid (H, B, 16): ONE 128-row q-tile per block, qt = 15 - z (heavy tiles first).
// id%8 = h%8 -> per-XCD K+V set = 4MB = L2-resident. LDS 50KB -> 3 blocks/CU.
__global__ __launch_bounds__(256, 3) void attn_kernel(const f16* __restrict__ Q,
                                                      const f16* __restrict__ Kg,
                                                      const f16* __restrict__ Vt,
                                                      f16* __restrict__ Z) {
    __shared__ __align__(16) f16 KL[2][64 * 64];
    __shared__ __align__(16) f16 VL[2][64 * 64];
    __shared__ __align__(16) f16 Pl[4][32][72];
    const int h = blockIdx.x, b = blockIdx.y;
    const int qt = 15 - (int)blockIdx.z; // heavy tiles dispatch first
    const int tid = threadIdx.x, w = tid >> 6, l = tid & 63, lr = l & 15, lg = l >> 4;
    const size_t base   = ((size_t)b * S_) * D_ + h * HD_;
    const size_t vtbase = ((size_t)(b * D_ + h * HD_)) * S_;
    const f16* __restrict__ Kbase = Kg + base;
    const f16* __restrict__ Vbase = Vt + vtbase;
    const float sc = 0.125f * 1.44269504f; // 1/sqrt(64) * log2(e)
    const int sw_xor = lr & 7;
    f16x8 onesv;
#pragma unroll
    for (int i = 0; i < 8; ++i) onesv[i] = (f16)1.0f;

    auto stageKV = [&](int buf, int t0) {
#pragma unroll
        for (int i = 0; i < 2; ++i) {
            const int c = i * 256 + tid;
            const int row = c >> 3, g16 = (c & 7) ^ (row & 7);
            f16* dstK = &KL[buf][(i * 256 + w * 64) * 8];
            f16* dstV = &VL[buf][(i * 256 + w * 64) * 8];
            gload_lds16(Kbase + (size_t)(t0 + row) * D_ + g16 * 8, dstK);
            gload_lds16(Vbase + (size_t)row * S_ + t0 + g16 * 8, dstV);
        }
    };

    const int q0 = qt * 128, wq0 = q0 + w * 32;
    const int ntw = ((wq0 + 31) >> 6) + 1;
    const int ntb = qt * 2 + 2;

    f16x8 qf[2][2];
#pragma unroll
    for (int mf = 0; mf < 2; ++mf)
#pragma unroll
        for (int kd = 0; kd < 2; ++kd)
            qf[mf][kd] = *reinterpret_cast<const f16x8*>(
                Q + base + (size_t)(wq0 + mf * 16 + lr) * D_ + kd * 32 + lg * 8);

    f32x4 zacc[2][4] = {};
    f32x4 lsv[2] = {};
    float mrun[2] = {-3.0e38f, -3.0e38f};

    stageKV(0, 0);
    for (int t = 0; t < ntb; ++t) {
        const int buf = t & 1;
        if (t + 1 < ntb) {
            stageKV(buf ^ 1, (t + 1) * 64);
            asm volatile("s_waitcnt vmcnt(4)" ::: "memory");
        } else {
            asm volatile("s_waitcnt vmcnt(0)" ::: "memory");
        }
        __builtin_amdgcn_s_barrier();
        if (t < ntw) {
            const int t0 = t * 64;
            f16x8 kf[2][4];
#pragma unroll
            for (int kd = 0; kd < 2; ++kd)
#pragma unroll
                for (int n = 0; n < 4; ++n)
                    kf[kd][n] = *reinterpret_cast<const f16x8*>(
                        &KL[buf][(n * 16 + lr) * 64 + (((kd * 4 + lg) ^ sw_xor) * 8)]);
            f32x4 sf[2][4] = {};
            __builtin_amdgcn_s_setprio(1);
#pragma unroll
            for (int kd = 0; kd < 2; ++kd)
#pragma unroll
                for (int n = 0; n < 4; ++n)
#pragma unroll
                    for (int mf = 0; mf < 2; ++mf)
                        sf[mf][n] = __builtin_amdgcn_mfma_f32_16x16x32_f16(kf[kd][n], qf[mf][kd], sf[mf][n], 0, 0, 0);
            __builtin_amdgcn_s_setprio(0);
            f16x8 vf[2][4];
#pragma unroll
            for (int kt = 0; kt < 2; ++kt)
#pragma unroll
                for (int n = 0; n < 4; ++n)
                    vf[kt][n] = *reinterpret_cast<const f16x8*>(
                        &VL[buf][(n * 16 + lr) * 64 + (((kt * 4 + lg) ^ sw_xor) * 8)]);
            if (t == ntw - 1) {
#pragma unroll
                for (int mf = 0; mf < 2; ++mf)
#pragma unroll
                    for (int n = 0; n < 4; ++n)
#pragma unroll
                        for (int r = 0; r < 4; ++r)
                            if ((t0 + n * 16 + lg * 4 + r) > (wq0 + mf * 16 + lr))
                                sf[mf][n][r] = -3.0e38f;
            }
#pragma unroll
            for (int mf = 0; mf < 2; ++mf) {
                f32x4 t4;
#pragma unroll
                for (int r = 0; r < 4; ++r)
                    t4[r] = fmaxf(fmaxf(sf[mf][0][r], sf[mf][1][r]), fmaxf(sf[mf][2][r], sf[mf][3][r]));
                float vmax = fmaxf(fmaxf(t4[0], t4[1]), fmaxf(t4[2], t4[3]));
                vmax = fmaxf(vmax, __shfl_xor(vmax, 16));
                vmax = fmaxf(vmax, __shfl_xor(vmax, 32));
                const float vs = vmax * sc;
                const bool norm = !__all(vs <= mrun[mf] + 10.0f);
                if (norm) {
                    const float mnew = fmaxf(mrun[mf], vs);
                    const float al = __builtin_amdgcn_exp2f(mrun[mf] - mnew);
                    mrun[mf] = mnew;
#pragma unroll
                    for (int r = 0; r < 4; ++r) {
                        const float ar = __shfl(al, lg * 4 + r);
#pragma unroll
                        for (int n = 0; n < 4; ++n) zacc[mf][n][r] *= ar;
                        lsv[mf][r] *= ar;
                    }
                }
#pragma unroll
                for (int n = 0; n < 4; ++n) {
                    f32x4 p;
#pragma unroll
                    for (int r = 0; r < 4; ++r)
                        p[r] = __builtin_amdgcn_exp2f(fmaf(sf[mf][n][r], sc, -mrun[mf]));
                    f16x4 pv;
#pragma unroll
                    for (int r = 0; r < 4; ++r) pv[r] = (f16)p[r];
                    *reinterpret_cast<f16x4*>(&Pl[w][mf * 16 + lr][n * 16 + lg * 4]) = pv;
                }
            }
#pragma unroll
            for (int kt = 0; kt < 2; ++kt) {
                f16x8 pa[2];
#pragma unroll
                for (int mf = 0; mf < 2; ++mf)
                    pa[mf] = *reinterpret_cast<const f16x8*>(&Pl[w][mf * 16 + lr][kt * 32 + lg * 8]);
                __builtin_amdgcn_s_setprio(1);
#pragma unroll
                for (int n = 0; n < 4; ++n)
#pragma unroll
                    for (int mf = 0; mf < 2; ++mf)
                        zacc[mf][n] = __builtin_amdgcn_mfma_f32_16x16x32_f16(pa[mf], vf[kt][n], zacc[mf][n], 0, 0, 0);
#pragma unroll
                for (int mf = 0; mf < 2; ++mf)
                    lsv[mf] = __builtin_amdgcn_mfma_f32_16x16x32_f16(pa[mf], onesv, lsv[mf], 0, 0, 0);
                __builtin_amdgcn_s_setprio(0);
            }
        }
        __builtin_amdgcn_s_barrier();
    }
#pragma unroll
    for (int mf = 0; mf < 2; ++mf) {
        f32x4 inv;
#pragma unroll
        for (int r = 0; r < 4; ++r) inv[r] = 1.0f / lsv[mf][r];
#pragma unroll
        for (int r = 0; r < 4; ++r)
#pragma unroll
            for (int n = 0; n < 4; ++n)
                Z[base + (size_t)(wq0 + mf * 16 + lg * 4 + r) * D_ + n * 16 + lr] =
                    (f16)(zacc[mf][n][r] * inv[r]);
    }
}

// ---------------------------------------------------------------- launcher
extern "C" void kernel_launch(void* const* d_in, const int* in_sizes, int n_in,
                              void* d_out, int out_size, void* d_ws, size_t ws_size,
                              hipStream_t stream) {
    const float* data    = (const float*)d_in[0];
    const float* context = (const float*)d_in[1];
    const float* Wq = (const float*)d_in[2];
    const float* bq = (const float*)d_in[3];
    const float* Wk = (const float*)d_in[4];
    const float* bk = (const float*)d_in[5];
    const float* Wv = (const float*)d_in[6];
    const float* bv = (const float*)d_in[7];
    const float* Wo = (const float*)d_in[8];
    const float* bo = (const float*)d_in[9];

    const size_t MD = (size_t)M_ * D_;
    const size_t DD = (size_t)D_ * D_;
    f16* dataB = (f16*)d_ws;
    f16* ctxB  = dataB + MD;
    f16* WqT   = ctxB + MD;   // WqT,WkT,WvT,WoT contiguous
    f16* WoT   = WqT + 3 * DD;
    f16* Qb    = WqT + 4 * DD;
    f16* Kb    = Qb + MD;
    f16* VtB   = Kb + MD;     // [B][H][HD][S]
    f16* Zb    = VtB + MD;

    const int n4 = (int)(MD / 4);
    cvt2_kernel<<<2048, 256, 0, stream>>>(data, context, dataB, n4);
    transpose_cvt4_kernel<<<dim3(32, 32, 4), 256, 0, stream>>>(Wq, Wk, Wv, Wo, WqT);

    (void)hipFuncSetAttribute(reinterpret_cast<const void*>(gemm3p<0>),
                              hipFuncAttributeMaxDynamicSharedMemorySize, 73728);
    (void)hipFuncSetAttribute(reinterpret_cast<const void*>(gemm3p<1>),
                              hipFuncAttributeMaxDynamicSharedMemorySize, 73728);

    // QKV: 768 blocks, segment order K,V,Q (co-resident K+V share A=context)
    gemm3p<0><<<768, 256, 73728, stream>>>(dataB, ctxB, WqT, bq, bk, bv,
                                           Qb, Kb, VtB, nullptr);

    attn_kernel<<<dim3(H_, B_, 16), 256, 0, stream>>>(Qb, Kb, VtB, Zb);

    gemm3p<1><<<256, 256, 73728, stream>>>(Zb, nullptr, WoT, bo, nullptr, nullptr,
                                           nullptr, nullptr, nullptr, (float*)d_out);
}